// Round 12
// baseline (352.689 us; speedup 1.0000x reference)
//
#include <hip/hip_runtime.h>
#include <cstdint>
#include <cstddef>

#define DEVI __device__ __forceinline__

typedef __attribute__((ext_vector_type(8))) short short8;
typedef __attribute__((ext_vector_type(4))) float f32x4;
typedef __bf16 bf16x8 __attribute__((ext_vector_type(8)));

DEVI float sigf(float x) { return 1.0f / (1.0f + __expf(-x)); }
DEVI float tanh_f(float x) { return 2.0f / (1.0f + __expf(-2.0f * x)) - 1.0f; }

DEVI short f2bf(float x) {
    uint32_t u = __builtin_bit_cast(uint32_t, x);
    u += 0x7FFFu + ((u >> 16) & 1u);   // RTNE
    return (short)(u >> 16);
}
DEVI float bf2f(short s) {
    uint32_t u = ((uint32_t)(unsigned short)s) << 16;
    return __builtin_bit_cast(float, u);
}

DEVI void gload16(const void* g, void* l) {
    __builtin_amdgcn_global_load_lds(
        (const __attribute__((address_space(1))) void*)g,
        (__attribute__((address_space(3))) void*)l, 16, 0, 0);
}

DEVI f32x4 mfma16(short8 a, short8 b, f32x4 c) {
    return __builtin_amdgcn_mfma_f32_16x16x32_bf16(
        __builtin_bit_cast(bf16x8, a), __builtin_bit_cast(bf16x8, b), c, 0, 0, 0);
}

// ---------------- fused prep: index scan + weights + x + logits zero ----------------

#define W_SLOTS   688128   // 4096*1344/8
#define WC_SLOTS  393216   // 1024*3072/8
#define XB_SLOTS  143360   // 3584*320/8
#define LG_SLOTS  6400     // 25600*4B /16
#define PREP_TOT  (W_SLOTS + WC_SLOTS + XB_SLOTS + LG_SLOTS)

__global__ __launch_bounds__(256) void prep_all(const int* __restrict__ index,
                                                const float* __restrict__ Wih,
                                                const float* __restrict__ Whh,
                                                const float* __restrict__ bih,
                                                const float* __restrict__ bhh,
                                                const float* __restrict__ Ww,
                                                const float* __restrict__ Wpw,
                                                const float* __restrict__ q,
                                                int* __restrict__ cum,
                                                int* __restrict__ bmap,
                                                short* __restrict__ Wstk,
                                                short* __restrict__ Wcat,
                                                short* __restrict__ xb,
                                                float* __restrict__ lgt) {
    __shared__ int sh[256];
    if (blockIdx.x == 0) {
        int t = threadIdx.x;
        int myidx = index[t];
        sh[t] = myidx;
        __syncthreads();
        for (int off = 1; off < 256; off <<= 1) {
            int v = (t >= off) ? sh[t - off] : 0;
            __syncthreads();
            sh[t] += v;
            __syncthreads();
        }
        cum[t + 1] = sh[t];
        if (t == 0) cum[0] = 0;
        int base = sh[t] - myidx;
        for (int j = 0; j < myidx; ++j) bmap[base + j] = t;
        bmap[sh[255] + t] = 0;    // 256 pad entries
        return;
    }
    int s = (blockIdx.x - 1) * 256 + threadIdx.x;
    if (s < W_SLOTS) {
        int n = s / 168, c8 = s - n * 168, kb = c8 * 8;
        int hblk = n >> 6, gate = (n >> 4) & 3, hl = n & 15;
        int on = gate * 1024 + hblk * 16 + hl;
        short8 o;
#pragma unroll
        for (int e = 0; e < 8; ++e) {
            int k = kb + e;
            float v;
            if (k < 300) v = Wih[on * 300 + k];
            else if (k == 300) v = bih[on] + bhh[on];
            else if (k < 320) v = 0.f;
            else v = Whh[on * 1024 + (k - 320)];
            o[e] = f2bf(v);
        }
        *(short8*)&Wstk[n * 1344 + kb] = o;
        return;
    }
    s -= W_SLOTS;
    if (s < WC_SLOTS) {
        int n = s / 384, c8 = s - n * 384, kb = c8 * 8;
        int hg = n >> 5, which = (n >> 4) & 1, hl = n & 15;
        int h = hg * 16 + hl;
        const float* src = (which ? Wpw : Ww) + (size_t)h * 3072 + kb;
        float4 v0 = *(const float4*)src;
        float4 v1 = *(const float4*)(src + 4);
        short8 o;
        o[0] = f2bf(v0.x); o[1] = f2bf(v0.y); o[2] = f2bf(v0.z); o[3] = f2bf(v0.w);
        o[4] = f2bf(v1.x); o[5] = f2bf(v1.y); o[6] = f2bf(v1.z); o[7] = f2bf(v1.w);
        *(short8*)&Wcat[(size_t)n * 3072 + kb] = o;
        return;
    }
    s -= WC_SLOTS;
    if (s < XB_SLOTS) {
        int row = s / 40, c8 = s - row * 40, eb = c8 * 8;
        int t = row / 256, b = row - t * 256;
        const float* qr = q + (size_t)(b * 14 + t) * 300;
        short8 o;
#pragma unroll
        for (int e = 0; e < 8; ++e) {
            int ee = eb + e;
            float v = (ee < 300) ? qr[ee] : (ee == 300 ? 1.0f : 0.0f);
            o[e] = f2bf(v);
        }
        *(short8*)&xb[(size_t)row * 320 + eb] = o;
        return;
    }
    s -= XB_SLOTS;
    if (s < LG_SLOTS) { ((f32x4*)lgt)[s] = f32x4{0.f, 0.f, 0.f, 0.f}; return; }
}

// ---------------- fused: xg GEMM (+t=0 cell) AND box compaction ----------------
// blocks [0,896): xg_gemm tiles (32 n-panels x 28 m-panels), MFMA-heavy.
// blocks [896, 896+25600): compact one box row, BW-bound. The two overlap.

__global__ __launch_bounds__(256) void compact_xg(const short* __restrict__ xb,   // [3584][320]
                                                  const short* __restrict__ Wstk, // [4096][1344]
                                                  short* __restrict__ xg,         // [3584][4096]
                                                  float* __restrict__ c,          // [256][1024]
                                                  short* __restrict__ hb1,        // [256][1024]
                                                  const float* __restrict__ box,
                                                  const int* __restrict__ index,
                                                  const int* __restrict__ cum,
                                                  short* __restrict__ Ac) {
    __shared__ __attribute__((aligned(16))) short As[128 * 64];
    __shared__ __attribute__((aligned(16))) short Bs[128 * 64];
    const int bid = blockIdx.x;
    if (bid >= 896) {
        // ---- compact part ----
        int m = bid - 896;                   // 25600
        int b = m / 100, j = m - b * 100;
        if (j >= index[b]) return;
        size_t dr = (size_t)(cum[b] + j);
        int t = threadIdx.x;
        const float* src = box + (size_t)m * 2048 + t * 8;
        float4 v0 = *(const float4*)src;
        float4 v1 = *(const float4*)(src + 4);
        short8 s;
        s[0] = f2bf(v0.x); s[1] = f2bf(v0.y); s[2] = f2bf(v0.z); s[3] = f2bf(v0.w);
        s[4] = f2bf(v1.x); s[5] = f2bf(v1.y); s[6] = f2bf(v1.z); s[7] = f2bf(v1.w);
        *(short8*)&Ac[dr * 2048 + t * 8] = s;
        return;
    }
    // ---- xg part ----
    const int tid = threadIdx.x, l = tid & 63, w = tid >> 6;
    const int n0 = (bid & 31) * 128;   // 32
    const int m0 = (bid >> 5) * 128;   // 28
    const int wm = w >> 1, wn = w & 1;

    const short* asrc[4];
    const short* bsrc[4];
    for (int i = 0; i < 4; i++) {
        int r = w * 32 + i * 8 + (l >> 3);
        int cs = (l & 7) ^ (r & 7);
        asrc[i] = xb + (size_t)(m0 + r) * 320 + cs * 8;
        bsrc[i] = Wstk + (size_t)(n0 + r) * 1344 + cs * 8;
    }

    f32x4 acc[4][4];
    for (int i = 0; i < 4; i++)
        for (int j = 0; j < 4; j++) acc[i][j] = f32x4{0.f, 0.f, 0.f, 0.f};

    for (int kt = 0; kt < 5; ++kt) {
        const int k0 = kt * 64;
        __syncthreads();
        for (int i = 0; i < 4; i++)
            gload16(asrc[i] + k0, &As[(w * 32 + i * 8) * 64]);
        for (int i = 0; i < 4; i++)
            gload16(bsrc[i] + k0, &Bs[(w * 32 + i * 8) * 64]);
        __syncthreads();
        for (int ks = 0; ks < 2; ++ks) {
            short8 a[4], b[4];
            for (int mf = 0; mf < 4; ++mf) {
                int m = wm * 64 + mf * 16 + (l & 15);
                int ca = (ks * 4 + (l >> 4)) ^ (m & 7);
                a[mf] = *(const short8*)&As[m * 64 + ca * 8];
            }
            for (int nf = 0; nf < 4; ++nf) {
                int n = wn * 64 + nf * 16 + (l & 15);
                int cb = (ks * 4 + (l >> 4)) ^ (n & 7);
                b[nf] = *(const short8*)&Bs[n * 64 + cb * 8];
            }
            for (int mf = 0; mf < 4; ++mf)
                for (int nf = 0; nf < 4; ++nf)
                    acc[mf][nf] = mfma16(a[mf], b[nf], acc[mf][nf]);
        }
    }
    const int hl = l & 15, hi = l >> 4;
    if (m0 < 256) {
        // t=0 fused cell update (h0 = c0 = 0)
        const int h = ((n0 + wn * 64) >> 6) * 16 + hl;
        for (int mf = 0; mf < 4; ++mf)
            for (int rg = 0; rg < 4; ++rg) {
                int b = m0 + wm * 64 + mf * 16 + hi * 4 + rg;
                float ig = acc[mf][0][rg];
                float gg = acc[mf][2][rg];
                float og = acc[mf][3][rg];
                float cn = sigf(ig) * tanh_f(gg);
                size_t off = (size_t)b * 1024 + h;
                c[off] = cn;
                hb1[off] = f2bf(sigf(og) * tanh_f(cn));
            }
    } else {
        for (int mf = 0; mf < 4; ++mf)
            for (int nf = 0; nf < 4; ++nf)
                for (int rg = 0; rg < 4; ++rg) {
                    int row = m0 + wm * 64 + mf * 16 + hi * 4 + rg;
                    int col = n0 + wn * 64 + nf * 16 + hl;
                    xg[(size_t)row * 4096 + col] = f2bf(acc[mf][nf][rg]);
                }
    }
}

// ---------------- LSTM recurrent step (R10 config: 512 x 128, BN'=64) ----------------

__global__ __launch_bounds__(128) void lstm_step(const short* __restrict__ hin,  // [256][1024]
                                                 const short* __restrict__ Wstk, // [4096][1344]
                                                 const short* __restrict__ xg_t, // [256][4096]
                                                 float* __restrict__ c,          // [256][1024]
                                                 short* __restrict__ hout) {
    __shared__ __attribute__((aligned(16))) short As[2][32 * 128];
    __shared__ __attribute__((aligned(16))) short Bs[2][64 * 128];
    const int tid = threadIdx.x, l = tid & 63, w = tid >> 6;
    const int hi = l >> 4, hl = l & 15;
    const int bid = blockIdx.x;             // 512
    const int xcd = bid & 7, ii = bid >> 3;
    const int ny = xcd * 8 + (ii & 7);      // n' panel [0,64)
    const int mx = ii >> 3;                 // m panel [0,8)
    const int m0 = mx * 32, n0g = ny * 64;

    f32x4 acc[4];
    for (int i = 0; i < 4; i++) acc[i] = f32x4{0.f, 0.f, 0.f, 0.f};

    const short* asrc[4];
    const short* bsrc[8];
    for (int i = 0; i < 4; i++) {
        int s = i * 128 + tid;
        int r = s >> 4, cs = s & 15;
        asrc[i] = hin + (size_t)(m0 + r) * 1024 + ((cs ^ (r & 15)) * 8);
    }
    for (int i = 0; i < 8; i++) {
        int s = i * 128 + tid;
        int r = s >> 4, cs = s & 15;
        bsrc[i] = Wstk + (size_t)(n0g + r) * 1344 + 320 + ((cs ^ (r & 15)) * 8);
    }
    for (int i = 0; i < 4; i++) gload16(asrc[i], &As[0][(i * 128 + tid) * 8]);
    for (int i = 0; i < 8; i++) gload16(bsrc[i], &Bs[0][(i * 128 + tid) * 8]);

    for (int kt = 0; kt < 8; ++kt) {
        const int cur = kt & 1;
        if (kt < 7) {
            const int k0 = (kt + 1) * 128;
            for (int i = 0; i < 4; i++)
                gload16(asrc[i] + k0, &As[cur ^ 1][(i * 128 + tid) * 8]);
            for (int i = 0; i < 8; i++)
                gload16(bsrc[i] + k0, &Bs[cur ^ 1][(i * 128 + tid) * 8]);
            asm volatile("s_waitcnt vmcnt(12)" ::: "memory");
        } else {
            asm volatile("s_waitcnt vmcnt(0)" ::: "memory");
        }
        __builtin_amdgcn_sched_barrier(0);
        __builtin_amdgcn_s_barrier();
        __builtin_amdgcn_sched_barrier(0);
#pragma unroll
        for (int ks = 0; ks < 4; ++ks) {
            const int mrow = w * 16 + hl;
            const int ca = (ks * 4 + hi) ^ hl;
            short8 a = *(const short8*)&As[cur][mrow * 128 + ca * 8];
#pragma unroll
            for (int nf = 0; nf < 4; ++nf) {
                const int nrow = nf * 16 + hl;
                short8 b = *(const short8*)&Bs[cur][nrow * 128 + ca * 8];
                acc[nf] = mfma16(a, b, acc[nf]);
            }
        }
        __builtin_amdgcn_sched_barrier(0);
        asm volatile("s_waitcnt lgkmcnt(0)" ::: "memory");
        __builtin_amdgcn_s_barrier();
        __builtin_amdgcn_sched_barrier(0);
    }

    const short* xr0 = xg_t + (size_t)(m0 + w * 16 + hi * 4) * 4096 + n0g + hl;
    for (int rg = 0; rg < 4; ++rg) {
        const short* xr = xr0 + (size_t)rg * 4096;
        float ig = acc[0][rg] + bf2f(xr[0]);
        float fg = acc[1][rg] + bf2f(xr[16]);
        float gg = acc[2][rg] + bf2f(xr[32]);
        float og = acc[3][rg] + bf2f(xr[48]);
        size_t off = (size_t)(m0 + w * 16 + hi * 4 + rg) * 1024 + ny * 16 + hl;
        float cn = sigf(fg) * c[off] + sigf(ig) * tanh_f(gg);
        c[off] = cn;
        hout[off] = f2bf(sigf(og) * tanh_f(cn));
    }
}

// ---------------- gated MLP: BM=256 x BN=128, T14 A-reg prefetch + B dbuf ----------------

// A(kt+1) loaded to registers during compute(kt) (bf16, no conversion);
// B(kt+1) gload16'd into Bs[cur^1]. vmcnt(0) waits only on loads issued one
// full compute-phase earlier -> latency hidden. LDS 64 KB -> 2 blocks/CU.
__global__ __launch_bounds__(512) void mlp_gemm(const short* __restrict__ Ac,   // [25600][2048]
                                                const short* __restrict__ hb,   // [256][1024]
                                                const short* __restrict__ Wcat, // [1024][3072]
                                                const int* __restrict__ mliveptr,
                                                const int* __restrict__ bmap,
                                                const float* __restrict__ Wb,
                                                const float* __restrict__ Wpb,
                                                const float* __restrict__ fw,
                                                float* __restrict__ logits) {
    __shared__ __attribute__((aligned(16))) short As[256 * 64];      // 32 KB
    __shared__ __attribute__((aligned(16))) short Bs[2][128 * 64];   // 32 KB
    const int Mlive = *mliveptr;
    const int tid = threadIdx.x, l = tid & 63, w = tid >> 6;      // w 0..7
    const int bid = blockIdx.x;              // 800
    const int xcd = bid & 7, ii = bid >> 3;  // ii 0..99
    const int x = ii & 7, q = ii >> 3;       // q 0..12
    const int y = q * 8 + xcd;
    const int n0 = x * 128, m0 = y * 256;
    if (m0 >= Mlive) return;
    const int wm = w >> 1, wn = w & 1;

    const short* asrc[4];
    const short* hsrc[4];
    int adst[4];
    const short* bsrc[2];
    int bdst[2];
    for (int i = 0; i < 4; i++) {
        int r = i * 64 + w * 8 + (l >> 3);           // 0..255
        int cs = (l & 7) ^ (r & 7);
        asrc[i] = Ac + (size_t)(m0 + r) * 2048 + cs * 8;
        hsrc[i] = hb + (size_t)bmap[m0 + r] * 1024 + cs * 8;
        adst[i] = (i * 64 + w * 8) * 64 + ((((l & 7) ^ ((w * 8 + (l >> 3)) & 7)) ^ ((w * 8 + (l >> 3)) & 7)) * 0);  // placeholder 0
    }
    // LDS dest for A: row r, chunk cc = (l&7)  -> swizzled offset (cc stays the
    // SOURCE-swizzled chunk; dest is linear in slot order, matching gload16 layout)
    for (int i = 0; i < 4; i++)
        adst[i] = (i * 64 + w * 8) * 64 + (l & 63) * 0;   // recomputed below
    // Recompute cleanly: slot layout identical to gload16 staging in R10:
    // thread (w,l) stages 16B at As[(i*64 + w*8)*64 + l*8] per wave-linear order.
    int adst2[4];
    for (int i = 0; i < 4; i++) adst2[i] = ((i * 64 + w * 8) * 64) + l * 8;
    for (int i = 0; i < 2; i++) {
        int r = i * 64 + w * 8 + (l >> 3);           // 0..127
        int cs = (l & 7) ^ (r & 7);
        bsrc[i] = Wcat + (size_t)(n0 + r) * 3072 + cs * 8;
        bdst[i] = (i * 64 + w * 8) * 64;
    }

    f32x4 acc[4][4];
    for (int i = 0; i < 4; i++)
        for (int j = 0; j < 4; j++) acc[i][j] = f32x4{0.f, 0.f, 0.f, 0.f};

    // prologue: A(0) -> regs, B(0) -> Bs[0]
    short8 areg[4];
#pragma unroll
    for (int i = 0; i < 4; i++) areg[i] = *(const short8*)asrc[i];
    for (int i = 0; i < 2; i++) gload16(bsrc[i], &Bs[0][bdst[i]]);

    for (int kt = 0; kt < 48; ++kt) {
        const int cur = kt & 1;
        // wait for A(kt)-regs and B(kt)-LDS (issued one iteration ago)
        asm volatile("s_waitcnt vmcnt(0)" ::: "memory");
        __builtin_amdgcn_sched_barrier(0);
        // commit A(kt) to LDS
#pragma unroll
        for (int i = 0; i < 4; i++) *(short8*)&As[adst2[i]] = areg[i];
        // prefetch kt+1
        if (kt < 47) {
            const int k1 = (kt + 1) * 64;
            for (int i = 0; i < 2; i++)
                gload16(bsrc[i] + k1, &Bs[cur ^ 1][bdst[i]]);
            if (kt + 1 < 32) {
#pragma unroll
                for (int i = 0; i < 4; i++) areg[i] = *(const short8*)(asrc[i] + k1);
            } else {
                const int kq = k1 - 2048;
#pragma unroll
                for (int i = 0; i < 4; i++) areg[i] = *(const short8*)(hsrc[i] + kq);
            }
        }
        __builtin_amdgcn_sched_barrier(0);
        asm volatile("s_waitcnt lgkmcnt(0)" ::: "memory");   // my ds_writes done
        __builtin_amdgcn_s_barrier();                         // staging visible
        __builtin_amdgcn_sched_barrier(0);
        for (int ks = 0; ks < 2; ++ks) {
            short8 a[4], b[4];
            for (int mf = 0; mf < 4; ++mf) {
                int m = wm * 64 + mf * 16 + (l & 15);   // 0..255
                int ca = (ks * 4 + (l >> 4)) ^ (m & 7);
                a[mf] = *(const short8*)&As[m * 64 + ca * 8];
            }
            for (int nf = 0; nf < 4; ++nf) {
                int n = wn * 64 + nf * 16 + (l & 15);   // 0..127
                int cb = (ks * 4 + (l >> 4)) ^ (n & 7);
                b[nf] = *(const short8*)&Bs[cur][n * 64 + cb * 8];
            }
            for (int mf = 0; mf < 4; ++mf)
                for (int nf = 0; nf < 4; ++nf)
                    acc[mf][nf] = mfma16(a[mf], b[nf], acc[mf][nf]);
        }
        __builtin_amdgcn_sched_barrier(0);
        asm volatile("s_waitcnt lgkmcnt(0)" ::: "memory");   // my ds_reads done
        __builtin_amdgcn_s_barrier();                         // As/Bs[cur^1] free
        __builtin_amdgcn_sched_barrier(0);
    }

    const int hl = l & 15, hi = l >> 4;
    for (int mf = 0; mf < 4; ++mf) {
        float part[4] = {0.f, 0.f, 0.f, 0.f};
        for (int p = 0; p < 2; ++p) {
            int ntg = (n0 + wn * 64) / 16 + 2 * p;
            int hg = ntg >> 1;
            int h = hg * 16 + hl;
            float fwv = fw[h], wbv = Wb[h], wpbv = Wpb[h];
            for (int rg = 0; rg < 4; ++rg) {
                float y2 = tanh_f(acc[mf][2 * p][rg] + wbv);
                float g2 = sigf(acc[mf][2 * p + 1][rg] + wpbv);
                part[rg] += y2 * g2 * fwv;
            }
        }
        for (int rg = 0; rg < 4; ++rg) {
            float v = part[rg];
            v += __shfl_xor(v, 1, 64);
            v += __shfl_xor(v, 2, 64);
            v += __shfl_xor(v, 4, 64);
            v += __shfl_xor(v, 8, 64);
            if (hl == 0) {
                int row = m0 + wm * 64 + mf * 16 + hi * 4 + rg;
                atomicAdd(&logits[row], v);
            }
        }
    }
}

__global__ __launch_bounds__(128) void reduce_out(const float* __restrict__ logits,
                                                  const int* __restrict__ index,
                                                  const int* __restrict__ cum,
                                                  float* __restrict__ out) {
    int b = blockIdx.x, t = threadIdx.x;
    int idx = index[b];
    int base = cum[b];
    float v = 0.f;
    if (t < 100 && t < idx) v = sigf(logits[base + t]);
    for (int m = 32; m; m >>= 1) v += __shfl_down(v, m, 64);
    __shared__ float s[2];
    if ((t & 63) == 0) s[t >> 6] = v;
    __syncthreads();
    if (t == 0) out[b] = s[0] + s[1];
}

// ---------------- host ----------------

extern "C" void kernel_launch(void* const* d_in, const int* in_sizes, int n_in,
                              void* d_out, int out_size, void* d_ws, size_t ws_size,
                              hipStream_t stream) {
    (void)in_sizes; (void)n_in; (void)out_size; (void)ws_size;
    const float* box = (const float*)d_in[2];
    const float* qf  = (const float*)d_in[3];
    const int* index = (const int*)d_in[5];
    const float* Wih = (const float*)d_in[6];
    const float* Whh = (const float*)d_in[7];
    const float* bih = (const float*)d_in[8];
    const float* bhh = (const float*)d_in[9];
    const float* Ww  = (const float*)d_in[10];
    const float* Wb  = (const float*)d_in[11];
    const float* Wpw = (const float*)d_in[12];
    const float* Wpb = (const float*)d_in[13];
    const float* fw  = (const float*)d_in[14];

    char* p = (char*)d_ws;
    short* Wstk = (short*)p;  p += (size_t)4096 * 1344 * 2;
    short* Wcat = (short*)p;  p += (size_t)1024 * 3072 * 2;
    short* xb   = (short*)p;  p += (size_t)3584 * 320 * 2;
    short* hb0  = (short*)p;  p += (size_t)256 * 1024 * 2;
    short* hb1  = (short*)p;  p += (size_t)256 * 1024 * 2;
    short* xg   = (short*)p;  p += (size_t)3584 * 4096 * 2;
    float* c    = (float*)p;  p += (size_t)256 * 1024 * 4;
    int*   cum  = (int*)p;    p += 260 * 4;
    int*   bmap = (int*)p;    p += (size_t)(25600 + 256) * 4;
    float* lgt  = (float*)p;  p += (size_t)25600 * 4;
    p = (char*)(((uintptr_t)p + 255) & ~(uintptr_t)255);
    short* Ac   = (short*)p;  p += (size_t)25600 * 2048 * 2;   // ~105 MB

    prep_all<<<1 + PREP_TOT / 256, 256, 0, stream>>>(
        index, Wih, Whh, bih, bhh, Ww, Wpw, qf, cum, bmap, Wstk, Wcat, xb, lgt);

    // fused: xg GEMM (+t=0 cell -> c, hb1) and box compaction -> Ac
    compact_xg<<<896 + 25600, 256, 0, stream>>>(xb, Wstk, xg, c, hb1,
                                                box, index, cum, Ac);

    short* hbuf[2] = {hb0, hb1};
    for (int t = 1; t < 14; ++t) {
        lstm_step<<<512, 128, 0, stream>>>(
            hbuf[t & 1], Wstk, xg + (size_t)t * 256 * 4096, c, hbuf[(t & 1) ^ 1]);
    }
    // t=13 reads hb1, writes hb0 -> final hidden state h_14 in hb0

    mlp_gemm<<<800, 512, 0, stream>>>(Ac, hb0, Wcat, cum + 256, bmap,
                                      Wb, Wpb, fw, lgt);
    reduce_out<<<256, 128, 0, stream>>>(lgt, index, cum, (float*)d_out);
}

// Round 13
// 297.548 us; speedup vs baseline: 1.1853x; 1.1853x over previous
//
#include <hip/hip_runtime.h>
#include <cstdint>
#include <cstddef>

#define DEVI __device__ __forceinline__

typedef __attribute__((ext_vector_type(8))) short short8;
typedef __attribute__((ext_vector_type(4))) float f32x4;
typedef __bf16 bf16x8 __attribute__((ext_vector_type(8)));

DEVI float sigf(float x) { return 1.0f / (1.0f + __expf(-x)); }
DEVI float tanh_f(float x) { return 2.0f / (1.0f + __expf(-2.0f * x)) - 1.0f; }

DEVI short f2bf(float x) {
    uint32_t u = __builtin_bit_cast(uint32_t, x);
    u += 0x7FFFu + ((u >> 16) & 1u);   // RTNE
    return (short)(u >> 16);
}
DEVI float bf2f(short s) {
    uint32_t u = ((uint32_t)(unsigned short)s) << 16;
    return __builtin_bit_cast(float, u);
}

DEVI void gload16(const void* g, void* l) {
    __builtin_amdgcn_global_load_lds(
        (const __attribute__((address_space(1))) void*)g,
        (__attribute__((address_space(3))) void*)l, 16, 0, 0);
}

DEVI f32x4 mfma16(short8 a, short8 b, f32x4 c) {
    return __builtin_amdgcn_mfma_f32_16x16x32_bf16(
        __builtin_bit_cast(bf16x8, a), __builtin_bit_cast(bf16x8, b), c, 0, 0, 0);
}

// ---------------- fused prep: index scan + weights + x + logits zero ----------------

#define W_SLOTS   688128   // 4096*1344/8
#define WC_SLOTS  393216   // 1024*3072/8
#define XB_SLOTS  143360   // 3584*320/8
#define LG_SLOTS  6400     // 25600*4B /16
#define PREP_TOT  (W_SLOTS + WC_SLOTS + XB_SLOTS + LG_SLOTS)

__global__ __launch_bounds__(256) void prep_all(const int* __restrict__ index,
                                                const float* __restrict__ Wih,
                                                const float* __restrict__ Whh,
                                                const float* __restrict__ bih,
                                                const float* __restrict__ bhh,
                                                const float* __restrict__ Ww,
                                                const float* __restrict__ Wpw,
                                                const float* __restrict__ q,
                                                int* __restrict__ cum,
                                                int* __restrict__ bmap,
                                                short* __restrict__ Wstk,
                                                short* __restrict__ Wcat,
                                                short* __restrict__ xb,
                                                float* __restrict__ lgt) {
    __shared__ int sh[256];
    if (blockIdx.x == 0) {
        int t = threadIdx.x;
        int myidx = index[t];
        sh[t] = myidx;
        __syncthreads();
        for (int off = 1; off < 256; off <<= 1) {
            int v = (t >= off) ? sh[t - off] : 0;
            __syncthreads();
            sh[t] += v;
            __syncthreads();
        }
        cum[t + 1] = sh[t];
        if (t == 0) cum[0] = 0;
        int base = sh[t] - myidx;
        for (int j = 0; j < myidx; ++j) bmap[base + j] = t;
        bmap[sh[255] + t] = 0;    // 256 pad entries
        return;
    }
    int s = (blockIdx.x - 1) * 256 + threadIdx.x;
    if (s < W_SLOTS) {
        int n = s / 168, c8 = s - n * 168, kb = c8 * 8;
        int hblk = n >> 6, gate = (n >> 4) & 3, hl = n & 15;
        int on = gate * 1024 + hblk * 16 + hl;
        short8 o;
#pragma unroll
        for (int e = 0; e < 8; ++e) {
            int k = kb + e;
            float v;
            if (k < 300) v = Wih[on * 300 + k];
            else if (k == 300) v = bih[on] + bhh[on];
            else if (k < 320) v = 0.f;
            else v = Whh[on * 1024 + (k - 320)];
            o[e] = f2bf(v);
        }
        *(short8*)&Wstk[n * 1344 + kb] = o;
        return;
    }
    s -= W_SLOTS;
    if (s < WC_SLOTS) {
        int n = s / 384, c8 = s - n * 384, kb = c8 * 8;
        int hg = n >> 5, which = (n >> 4) & 1, hl = n & 15;
        int h = hg * 16 + hl;
        const float* src = (which ? Wpw : Ww) + (size_t)h * 3072 + kb;
        float4 v0 = *(const float4*)src;
        float4 v1 = *(const float4*)(src + 4);
        short8 o;
        o[0] = f2bf(v0.x); o[1] = f2bf(v0.y); o[2] = f2bf(v0.z); o[3] = f2bf(v0.w);
        o[4] = f2bf(v1.x); o[5] = f2bf(v1.y); o[6] = f2bf(v1.z); o[7] = f2bf(v1.w);
        *(short8*)&Wcat[(size_t)n * 3072 + kb] = o;
        return;
    }
    s -= WC_SLOTS;
    if (s < XB_SLOTS) {
        int row = s / 40, c8 = s - row * 40, eb = c8 * 8;
        int t = row / 256, b = row - t * 256;
        const float* qr = q + (size_t)(b * 14 + t) * 300;
        short8 o;
#pragma unroll
        for (int e = 0; e < 8; ++e) {
            int ee = eb + e;
            float v = (ee < 300) ? qr[ee] : (ee == 300 ? 1.0f : 0.0f);
            o[e] = f2bf(v);
        }
        *(short8*)&xb[(size_t)row * 320 + eb] = o;
        return;
    }
    s -= XB_SLOTS;
    if (s < LG_SLOTS) { ((f32x4*)lgt)[s] = f32x4{0.f, 0.f, 0.f, 0.f}; return; }
}

// ---------------- fused: xg GEMM (+t=0 cell) AND box compaction ----------------
// blocks [0,896): xg_gemm tiles (32 n-panels x 28 m-panels), MFMA-heavy.
// blocks [896, 896+25600): compact one box row, BW-bound. The two overlap.

__global__ __launch_bounds__(256) void compact_xg(const short* __restrict__ xb,   // [3584][320]
                                                  const short* __restrict__ Wstk, // [4096][1344]
                                                  short* __restrict__ xg,         // [3584][4096]
                                                  float* __restrict__ c,          // [256][1024]
                                                  short* __restrict__ hb1,        // [256][1024]
                                                  const float* __restrict__ box,
                                                  const int* __restrict__ index,
                                                  const int* __restrict__ cum,
                                                  short* __restrict__ Ac) {
    __shared__ __attribute__((aligned(16))) short As[128 * 64];
    __shared__ __attribute__((aligned(16))) short Bs[128 * 64];
    const int bid = blockIdx.x;
    if (bid >= 896) {
        // ---- compact part ----
        int m = bid - 896;                   // 25600
        int b = m / 100, j = m - b * 100;
        if (j >= index[b]) return;
        size_t dr = (size_t)(cum[b] + j);
        int t = threadIdx.x;
        const float* src = box + (size_t)m * 2048 + t * 8;
        float4 v0 = *(const float4*)src;
        float4 v1 = *(const float4*)(src + 4);
        short8 s;
        s[0] = f2bf(v0.x); s[1] = f2bf(v0.y); s[2] = f2bf(v0.z); s[3] = f2bf(v0.w);
        s[4] = f2bf(v1.x); s[5] = f2bf(v1.y); s[6] = f2bf(v1.z); s[7] = f2bf(v1.w);
        *(short8*)&Ac[dr * 2048 + t * 8] = s;
        return;
    }
    // ---- xg part ----
    const int tid = threadIdx.x, l = tid & 63, w = tid >> 6;
    const int n0 = (bid & 31) * 128;   // 32
    const int m0 = (bid >> 5) * 128;   // 28
    const int wm = w >> 1, wn = w & 1;

    const short* asrc[4];
    const short* bsrc[4];
    for (int i = 0; i < 4; i++) {
        int r = w * 32 + i * 8 + (l >> 3);
        int cs = (l & 7) ^ (r & 7);
        asrc[i] = xb + (size_t)(m0 + r) * 320 + cs * 8;
        bsrc[i] = Wstk + (size_t)(n0 + r) * 1344 + cs * 8;
    }

    f32x4 acc[4][4];
    for (int i = 0; i < 4; i++)
        for (int j = 0; j < 4; j++) acc[i][j] = f32x4{0.f, 0.f, 0.f, 0.f};

    for (int kt = 0; kt < 5; ++kt) {
        const int k0 = kt * 64;
        __syncthreads();
        for (int i = 0; i < 4; i++)
            gload16(asrc[i] + k0, &As[(w * 32 + i * 8) * 64]);
        for (int i = 0; i < 4; i++)
            gload16(bsrc[i] + k0, &Bs[(w * 32 + i * 8) * 64]);
        __syncthreads();
        for (int ks = 0; ks < 2; ++ks) {
            short8 a[4], b[4];
            for (int mf = 0; mf < 4; ++mf) {
                int m = wm * 64 + mf * 16 + (l & 15);
                int ca = (ks * 4 + (l >> 4)) ^ (m & 7);
                a[mf] = *(const short8*)&As[m * 64 + ca * 8];
            }
            for (int nf = 0; nf < 4; ++nf) {
                int n = wn * 64 + nf * 16 + (l & 15);
                int cb = (ks * 4 + (l >> 4)) ^ (n & 7);
                b[nf] = *(const short8*)&Bs[n * 64 + cb * 8];
            }
            for (int mf = 0; mf < 4; ++mf)
                for (int nf = 0; nf < 4; ++nf)
                    acc[mf][nf] = mfma16(a[mf], b[nf], acc[mf][nf]);
        }
    }
    const int hl = l & 15, hi = l >> 4;
    if (m0 < 256) {
        // t=0 fused cell update (h0 = c0 = 0)
        const int h = ((n0 + wn * 64) >> 6) * 16 + hl;
        for (int mf = 0; mf < 4; ++mf)
            for (int rg = 0; rg < 4; ++rg) {
                int b = m0 + wm * 64 + mf * 16 + hi * 4 + rg;
                float ig = acc[mf][0][rg];
                float gg = acc[mf][2][rg];
                float og = acc[mf][3][rg];
                float cn = sigf(ig) * tanh_f(gg);
                size_t off = (size_t)b * 1024 + h;
                c[off] = cn;
                hb1[off] = f2bf(sigf(og) * tanh_f(cn));
            }
    } else {
        for (int mf = 0; mf < 4; ++mf)
            for (int nf = 0; nf < 4; ++nf)
                for (int rg = 0; rg < 4; ++rg) {
                    int row = m0 + wm * 64 + mf * 16 + hi * 4 + rg;
                    int col = n0 + wn * 64 + nf * 16 + hl;
                    xg[(size_t)row * 4096 + col] = f2bf(acc[mf][nf][rg]);
                }
    }
}

// ---------------- LSTM recurrent step (R10 config: 512 x 128, BN'=64) ----------------

__global__ __launch_bounds__(128) void lstm_step(const short* __restrict__ hin,  // [256][1024]
                                                 const short* __restrict__ Wstk, // [4096][1344]
                                                 const short* __restrict__ xg_t, // [256][4096]
                                                 float* __restrict__ c,          // [256][1024]
                                                 short* __restrict__ hout) {
    __shared__ __attribute__((aligned(16))) short As[2][32 * 128];
    __shared__ __attribute__((aligned(16))) short Bs[2][64 * 128];
    const int tid = threadIdx.x, l = tid & 63, w = tid >> 6;
    const int hi = l >> 4, hl = l & 15;
    const int bid = blockIdx.x;             // 512
    const int xcd = bid & 7, ii = bid >> 3;
    const int ny = xcd * 8 + (ii & 7);      // n' panel [0,64)
    const int mx = ii >> 3;                 // m panel [0,8)
    const int m0 = mx * 32, n0g = ny * 64;

    f32x4 acc[4];
    for (int i = 0; i < 4; i++) acc[i] = f32x4{0.f, 0.f, 0.f, 0.f};

    const short* asrc[4];
    const short* bsrc[8];
    for (int i = 0; i < 4; i++) {
        int s = i * 128 + tid;
        int r = s >> 4, cs = s & 15;
        asrc[i] = hin + (size_t)(m0 + r) * 1024 + ((cs ^ (r & 15)) * 8);
    }
    for (int i = 0; i < 8; i++) {
        int s = i * 128 + tid;
        int r = s >> 4, cs = s & 15;
        bsrc[i] = Wstk + (size_t)(n0g + r) * 1344 + 320 + ((cs ^ (r & 15)) * 8);
    }
    for (int i = 0; i < 4; i++) gload16(asrc[i], &As[0][(i * 128 + tid) * 8]);
    for (int i = 0; i < 8; i++) gload16(bsrc[i], &Bs[0][(i * 128 + tid) * 8]);

    for (int kt = 0; kt < 8; ++kt) {
        const int cur = kt & 1;
        if (kt < 7) {
            const int k0 = (kt + 1) * 128;
            for (int i = 0; i < 4; i++)
                gload16(asrc[i] + k0, &As[cur ^ 1][(i * 128 + tid) * 8]);
            for (int i = 0; i < 8; i++)
                gload16(bsrc[i] + k0, &Bs[cur ^ 1][(i * 128 + tid) * 8]);
            asm volatile("s_waitcnt vmcnt(12)" ::: "memory");
        } else {
            asm volatile("s_waitcnt vmcnt(0)" ::: "memory");
        }
        __builtin_amdgcn_sched_barrier(0);
        __builtin_amdgcn_s_barrier();
        __builtin_amdgcn_sched_barrier(0);
#pragma unroll
        for (int ks = 0; ks < 4; ++ks) {
            const int mrow = w * 16 + hl;
            const int ca = (ks * 4 + hi) ^ hl;
            short8 a = *(const short8*)&As[cur][mrow * 128 + ca * 8];
#pragma unroll
            for (int nf = 0; nf < 4; ++nf) {
                const int nrow = nf * 16 + hl;
                short8 b = *(const short8*)&Bs[cur][nrow * 128 + ca * 8];
                acc[nf] = mfma16(a, b, acc[nf]);
            }
        }
        __builtin_amdgcn_sched_barrier(0);
        asm volatile("s_waitcnt lgkmcnt(0)" ::: "memory");
        __builtin_amdgcn_s_barrier();
        __builtin_amdgcn_sched_barrier(0);
    }

    const short* xr0 = xg_t + (size_t)(m0 + w * 16 + hi * 4) * 4096 + n0g + hl;
    for (int rg = 0; rg < 4; ++rg) {
        const short* xr = xr0 + (size_t)rg * 4096;
        float ig = acc[0][rg] + bf2f(xr[0]);
        float fg = acc[1][rg] + bf2f(xr[16]);
        float gg = acc[2][rg] + bf2f(xr[32]);
        float og = acc[3][rg] + bf2f(xr[48]);
        size_t off = (size_t)(m0 + w * 16 + hi * 4 + rg) * 1024 + ny * 16 + hl;
        float cn = sigf(fg) * c[off] + sigf(ig) * tanh_f(gg);
        c[off] = cn;
        hout[off] = f2bf(sigf(og) * tanh_f(cn));
    }
}

// ---------------- gated MLP: BM=256 x BN=128, 8 waves, single-buffer (R10) ----------------

__global__ __launch_bounds__(512) void mlp_gemm(const short* __restrict__ Ac,   // [25600][2048]
                                                const short* __restrict__ hb,   // [256][1024]
                                                const short* __restrict__ Wcat, // [1024][3072]
                                                const int* __restrict__ mliveptr,
                                                const int* __restrict__ bmap,
                                                const float* __restrict__ Wb,
                                                const float* __restrict__ Wpb,
                                                const float* __restrict__ fw,
                                                float* __restrict__ logits) {
    __shared__ __attribute__((aligned(16))) short As[256 * 64];   // 32 KB
    __shared__ __attribute__((aligned(16))) short Bs[128 * 64];   // 16 KB
    const int Mlive = *mliveptr;
    const int tid = threadIdx.x, l = tid & 63, w = tid >> 6;      // w 0..7
    const int bid = blockIdx.x;              // 800
    const int xcd = bid & 7, ii = bid >> 3;  // ii 0..99
    const int x = ii & 7, q = ii >> 3;       // q 0..12
    const int y = q * 8 + xcd;
    const int n0 = x * 128, m0 = y * 256;
    if (m0 >= Mlive) return;
    const int wm = w >> 1, wn = w & 1;

    const short* asrc[4];
    const short* hsrc[4];
    int adst[4];
    const short* bsrc[2];
    int bdst[2];
    for (int i = 0; i < 4; i++) {
        int r = i * 64 + w * 8 + (l >> 3);           // 0..255
        int cs = (l & 7) ^ (r & 7);
        asrc[i] = Ac + (size_t)(m0 + r) * 2048 + cs * 8;
        hsrc[i] = hb + (size_t)bmap[m0 + r] * 1024 + cs * 8;
        adst[i] = (i * 64 + w * 8) * 64;
    }
    for (int i = 0; i < 2; i++) {
        int r = i * 64 + w * 8 + (l >> 3);           // 0..127
        int cs = (l & 7) ^ (r & 7);
        bsrc[i] = Wcat + (size_t)(n0 + r) * 3072 + cs * 8;
        bdst[i] = (i * 64 + w * 8) * 64;
    }

    f32x4 acc[4][4];
    for (int i = 0; i < 4; i++)
        for (int j = 0; j < 4; j++) acc[i][j] = f32x4{0.f, 0.f, 0.f, 0.f};

    for (int kt = 0; kt < 48; ++kt) {
        const int k0 = kt * 64;
        __syncthreads();
        if (kt < 32) {
            for (int i = 0; i < 4; i++)
                gload16(asrc[i] + k0, &As[adst[i]]);
        } else {
            const int kq = k0 - 2048;
            for (int i = 0; i < 4; i++)
                gload16(hsrc[i] + kq, &As[adst[i]]);
        }
        for (int i = 0; i < 2; i++)
            gload16(bsrc[i] + k0, &Bs[bdst[i]]);
        __syncthreads();
        for (int ks = 0; ks < 2; ++ks) {
            short8 a[4], b[4];
            for (int mf = 0; mf < 4; ++mf) {
                int m = wm * 64 + mf * 16 + (l & 15);   // 0..255
                int ca = (ks * 4 + (l >> 4)) ^ (m & 7);
                a[mf] = *(const short8*)&As[m * 64 + ca * 8];
            }
            for (int nf = 0; nf < 4; ++nf) {
                int n = wn * 64 + nf * 16 + (l & 15);   // 0..127
                int cb = (ks * 4 + (l >> 4)) ^ (n & 7);
                b[nf] = *(const short8*)&Bs[n * 64 + cb * 8];
            }
            for (int mf = 0; mf < 4; ++mf)
                for (int nf = 0; nf < 4; ++nf)
                    acc[mf][nf] = mfma16(a[mf], b[nf], acc[mf][nf]);
        }
    }

    const int hl = l & 15, hi = l >> 4;
    for (int mf = 0; mf < 4; ++mf) {
        float part[4] = {0.f, 0.f, 0.f, 0.f};
        for (int p = 0; p < 2; ++p) {
            int ntg = (n0 + wn * 64) / 16 + 2 * p;
            int hg = ntg >> 1;
            int h = hg * 16 + hl;
            float fwv = fw[h], wbv = Wb[h], wpbv = Wpb[h];
            for (int rg = 0; rg < 4; ++rg) {
                float y2 = tanh_f(acc[mf][2 * p][rg] + wbv);
                float g2 = sigf(acc[mf][2 * p + 1][rg] + wpbv);
                part[rg] += y2 * g2 * fwv;
            }
        }
        for (int rg = 0; rg < 4; ++rg) {
            float v = part[rg];
            v += __shfl_xor(v, 1, 64);
            v += __shfl_xor(v, 2, 64);
            v += __shfl_xor(v, 4, 64);
            v += __shfl_xor(v, 8, 64);
            if (hl == 0) {
                int row = m0 + wm * 64 + mf * 16 + hi * 4 + rg;
                atomicAdd(&logits[row], v);
            }
        }
    }
}

__global__ __launch_bounds__(128) void reduce_out(const float* __restrict__ logits,
                                                  const int* __restrict__ index,
                                                  const int* __restrict__ cum,
                                                  float* __restrict__ out) {
    int b = blockIdx.x, t = threadIdx.x;
    int idx = index[b];
    int base = cum[b];
    float v = 0.f;
    if (t < 100 && t < idx) v = sigf(logits[base + t]);
    for (int m = 32; m; m >>= 1) v += __shfl_down(v, m, 64);
    __shared__ float s[2];
    if ((t & 63) == 0) s[t >> 6] = v;
    __syncthreads();
    if (t == 0) out[b] = s[0] + s[1];
}

// ---------------- host ----------------

extern "C" void kernel_launch(void* const* d_in, const int* in_sizes, int n_in,
                              void* d_out, int out_size, void* d_ws, size_t ws_size,
                              hipStream_t stream) {
    (void)in_sizes; (void)n_in; (void)out_size; (void)ws_size;
    const float* box = (const float*)d_in[2];
    const float* qf  = (const float*)d_in[3];
    const int* index = (const int*)d_in[5];
    const float* Wih = (const float*)d_in[6];
    const float* Whh = (const float*)d_in[7];
    const float* bih = (const float*)d_in[8];
    const float* bhh = (const float*)d_in[9];
    const float* Ww  = (const float*)d_in[10];
    const float* Wb  = (const float*)d_in[11];
    const float* Wpw = (const float*)d_in[12];
    const float* Wpb = (const float*)d_in[13];
    const float* fw  = (const float*)d_in[14];

    char* p = (char*)d_ws;
    short* Wstk = (short*)p;  p += (size_t)4096 * 1344 * 2;
    short* Wcat = (short*)p;  p += (size_t)1024 * 3072 * 2;
    short* xb   = (short*)p;  p += (size_t)3584 * 320 * 2;
    short* hb0  = (short*)p;  p += (size_t)256 * 1024 * 2;
    short* hb1  = (short*)p;  p += (size_t)256 * 1024 * 2;
    short* xg   = (short*)p;  p += (size_t)3584 * 4096 * 2;
    float* c    = (float*)p;  p += (size_t)256 * 1024 * 4;
    int*   cum  = (int*)p;    p += 260 * 4;
    int*   bmap = (int*)p;    p += (size_t)(25600 + 256) * 4;
    float* lgt  = (float*)p;  p += (size_t)25600 * 4;
    p = (char*)(((uintptr_t)p + 255) & ~(uintptr_t)255);
    short* Ac   = (short*)p;  p += (size_t)25600 * 2048 * 2;   // ~105 MB

    prep_all<<<1 + PREP_TOT / 256, 256, 0, stream>>>(
        index, Wih, Whh, bih, bhh, Ww, Wpw, qf, cum, bmap, Wstk, Wcat, xb, lgt);

    // fused: xg GEMM (+t=0 cell -> c, hb1) and box compaction -> Ac
    compact_xg<<<896 + 25600, 256, 0, stream>>>(xb, Wstk, xg, c, hb1,
                                                box, index, cum, Ac);

    short* hbuf[2] = {hb0, hb1};
    for (int t = 1; t < 14; ++t) {
        lstm_step<<<512, 128, 0, stream>>>(
            hbuf[t & 1], Wstk, xg + (size_t)t * 256 * 4096, c, hbuf[(t & 1) ^ 1]);
    }
    // t=13 reads hb1, writes hb0 -> final hidden state h_14 in hb0

    mlp_gemm<<<800, 512, 0, stream>>>(Ac, hb0, Wcat, cum + 256, bmap,
                                      Wb, Wpb, fw, lgt);
    reduce_out<<<256, 128, 0, stream>>>(lgt, index, cum, (float*)d_out);
}

// Round 14
// 292.506 us; speedup vs baseline: 1.2057x; 1.0172x over previous
//
#include <hip/hip_runtime.h>
#include <cstdint>
#include <cstddef>

#define DEVI __device__ __forceinline__

typedef __attribute__((ext_vector_type(8))) short short8;
typedef __attribute__((ext_vector_type(4))) float f32x4;
typedef __bf16 bf16x8 __attribute__((ext_vector_type(8)));

DEVI float sigf(float x) { return 1.0f / (1.0f + __expf(-x)); }
DEVI float tanh_f(float x) { return 2.0f / (1.0f + __expf(-2.0f * x)) - 1.0f; }

DEVI short f2bf(float x) {
    uint32_t u = __builtin_bit_cast(uint32_t, x);
    u += 0x7FFFu + ((u >> 16) & 1u);   // RTNE
    return (short)(u >> 16);
}
DEVI float bf2f(short s) {
    uint32_t u = ((uint32_t)(unsigned short)s) << 16;
    return __builtin_bit_cast(float, u);
}

DEVI void gload16(const void* g, void* l) {
    __builtin_amdgcn_global_load_lds(
        (const __attribute__((address_space(1))) void*)g,
        (__attribute__((address_space(3))) void*)l, 16, 0, 0);
}

DEVI f32x4 mfma16(short8 a, short8 b, f32x4 c) {
    return __builtin_amdgcn_mfma_f32_16x16x32_bf16(
        __builtin_bit_cast(bf16x8, a), __builtin_bit_cast(bf16x8, b), c, 0, 0, 0);
}

// ---------------- prep: index scan + Wstk + xb + logits zero ----------------
// (Wcat conversion moved into compact_xg where it overlaps MFMA work.)

#define W_SLOTS   688128   // 4096*1344/8
#define WC_SLOTS  393216   // 1024*3072/8
#define XB_SLOTS  143360   // 3584*320/8
#define LG_SLOTS  6400     // 25600*4B /16
#define PREP_TOT  (W_SLOTS + XB_SLOTS + LG_SLOTS)   // 837888 = 3273*256

__global__ __launch_bounds__(256) void prep_all(const int* __restrict__ index,
                                                const float* __restrict__ Wih,
                                                const float* __restrict__ Whh,
                                                const float* __restrict__ bih,
                                                const float* __restrict__ bhh,
                                                const float* __restrict__ q,
                                                int* __restrict__ cum,
                                                int* __restrict__ bmap,
                                                short* __restrict__ Wstk,
                                                short* __restrict__ xb,
                                                float* __restrict__ lgt) {
    __shared__ int sh[256];
    if (blockIdx.x == 0) {
        int t = threadIdx.x;
        int myidx = index[t];
        sh[t] = myidx;
        __syncthreads();
        for (int off = 1; off < 256; off <<= 1) {
            int v = (t >= off) ? sh[t - off] : 0;
            __syncthreads();
            sh[t] += v;
            __syncthreads();
        }
        cum[t + 1] = sh[t];
        if (t == 0) cum[0] = 0;
        int base = sh[t] - myidx;
        for (int j = 0; j < myidx; ++j) bmap[base + j] = t;
        bmap[sh[255] + t] = 0;    // 256 pad entries
        return;
    }
    int s = (blockIdx.x - 1) * 256 + threadIdx.x;
    if (s < W_SLOTS) {
        int n = s / 168, c8 = s - n * 168, kb = c8 * 8;
        int hblk = n >> 6, gate = (n >> 4) & 3, hl = n & 15;
        int on = gate * 1024 + hblk * 16 + hl;
        short8 o;
#pragma unroll
        for (int e = 0; e < 8; ++e) {
            int k = kb + e;
            float v;
            if (k < 300) v = Wih[on * 300 + k];
            else if (k == 300) v = bih[on] + bhh[on];
            else if (k < 320) v = 0.f;
            else v = Whh[on * 1024 + (k - 320)];
            o[e] = f2bf(v);
        }
        *(short8*)&Wstk[n * 1344 + kb] = o;
        return;
    }
    s -= W_SLOTS;
    if (s < XB_SLOTS) {
        int row = s / 40, c8 = s - row * 40, eb = c8 * 8;
        int t = row / 256, b = row - t * 256;
        const float* qr = q + (size_t)(b * 14 + t) * 300;
        short8 o;
#pragma unroll
        for (int e = 0; e < 8; ++e) {
            int ee = eb + e;
            float v = (ee < 300) ? qr[ee] : (ee == 300 ? 1.0f : 0.0f);
            o[e] = f2bf(v);
        }
        *(short8*)&xb[(size_t)row * 320 + eb] = o;
        return;
    }
    s -= XB_SLOTS;
    if (s < LG_SLOTS) { ((f32x4*)lgt)[s] = f32x4{0.f, 0.f, 0.f, 0.f}; return; }
}

// ---------------- fused: xg GEMM (+t=0 cell), box compaction, Wcat prep ----------------
// blocks [0,896): xg_gemm tiles (MFMA-heavy).
// blocks [896, 896+25600): compact one box row (BW-bound).
// blocks [26496, 26496+1536): Wcat conversion (BW-bound; consumed by mlp_gemm).

__global__ __launch_bounds__(256) void compact_xg(const short* __restrict__ xb,   // [3584][320]
                                                  const short* __restrict__ Wstk, // [4096][1344]
                                                  short* __restrict__ xg,         // [3584][4096]
                                                  float* __restrict__ c,          // [256][1024]
                                                  short* __restrict__ hb1,        // [256][1024]
                                                  const float* __restrict__ box,
                                                  const int* __restrict__ index,
                                                  const int* __restrict__ cum,
                                                  short* __restrict__ Ac,
                                                  const float* __restrict__ Ww,
                                                  const float* __restrict__ Wpw,
                                                  short* __restrict__ Wcat) {
    __shared__ __attribute__((aligned(16))) short As[128 * 64];
    __shared__ __attribute__((aligned(16))) short Bs[128 * 64];
    const int bid = blockIdx.x;
    if (bid >= 896 + 25600) {
        // ---- Wcat part: 1536 blocks x 256 threads = WC_SLOTS short8 slots ----
        int s = (bid - 896 - 25600) * 256 + threadIdx.x;
        int n = s / 384, c8 = s - n * 384, kb = c8 * 8;
        int hg = n >> 5, which = (n >> 4) & 1, hl = n & 15;
        int h = hg * 16 + hl;
        const float* src = (which ? Wpw : Ww) + (size_t)h * 3072 + kb;
        float4 v0 = *(const float4*)src;
        float4 v1 = *(const float4*)(src + 4);
        short8 o;
        o[0] = f2bf(v0.x); o[1] = f2bf(v0.y); o[2] = f2bf(v0.z); o[3] = f2bf(v0.w);
        o[4] = f2bf(v1.x); o[5] = f2bf(v1.y); o[6] = f2bf(v1.z); o[7] = f2bf(v1.w);
        *(short8*)&Wcat[(size_t)n * 3072 + kb] = o;
        return;
    }
    if (bid >= 896) {
        // ---- compact part ----
        int m = bid - 896;                   // 25600
        int b = m / 100, j = m - b * 100;
        if (j >= index[b]) return;
        size_t dr = (size_t)(cum[b] + j);
        int t = threadIdx.x;
        const float* src = box + (size_t)m * 2048 + t * 8;
        float4 v0 = *(const float4*)src;
        float4 v1 = *(const float4*)(src + 4);
        short8 s;
        s[0] = f2bf(v0.x); s[1] = f2bf(v0.y); s[2] = f2bf(v0.z); s[3] = f2bf(v0.w);
        s[4] = f2bf(v1.x); s[5] = f2bf(v1.y); s[6] = f2bf(v1.z); s[7] = f2bf(v1.w);
        *(short8*)&Ac[dr * 2048 + t * 8] = s;
        return;
    }
    // ---- xg part ----
    const int tid = threadIdx.x, l = tid & 63, w = tid >> 6;
    const int n0 = (bid & 31) * 128;   // 32
    const int m0 = (bid >> 5) * 128;   // 28
    const int wm = w >> 1, wn = w & 1;

    const short* asrc[4];
    const short* bsrc[4];
    for (int i = 0; i < 4; i++) {
        int r = w * 32 + i * 8 + (l >> 3);
        int cs = (l & 7) ^ (r & 7);
        asrc[i] = xb + (size_t)(m0 + r) * 320 + cs * 8;
        bsrc[i] = Wstk + (size_t)(n0 + r) * 1344 + cs * 8;
    }

    f32x4 acc[4][4];
    for (int i = 0; i < 4; i++)
        for (int j = 0; j < 4; j++) acc[i][j] = f32x4{0.f, 0.f, 0.f, 0.f};

    for (int kt = 0; kt < 5; ++kt) {
        const int k0 = kt * 64;
        __syncthreads();
        for (int i = 0; i < 4; i++)
            gload16(asrc[i] + k0, &As[(w * 32 + i * 8) * 64]);
        for (int i = 0; i < 4; i++)
            gload16(bsrc[i] + k0, &Bs[(w * 32 + i * 8) * 64]);
        __syncthreads();
        for (int ks = 0; ks < 2; ++ks) {
            short8 a[4], b[4];
            for (int mf = 0; mf < 4; ++mf) {
                int m = wm * 64 + mf * 16 + (l & 15);
                int ca = (ks * 4 + (l >> 4)) ^ (m & 7);
                a[mf] = *(const short8*)&As[m * 64 + ca * 8];
            }
            for (int nf = 0; nf < 4; ++nf) {
                int n = wn * 64 + nf * 16 + (l & 15);
                int cb = (ks * 4 + (l >> 4)) ^ (n & 7);
                b[nf] = *(const short8*)&Bs[n * 64 + cb * 8];
            }
            for (int mf = 0; mf < 4; ++mf)
                for (int nf = 0; nf < 4; ++nf)
                    acc[mf][nf] = mfma16(a[mf], b[nf], acc[mf][nf]);
        }
    }
    const int hl = l & 15, hi = l >> 4;
    if (m0 < 256) {
        // t=0 fused cell update (h0 = c0 = 0)
        const int h = ((n0 + wn * 64) >> 6) * 16 + hl;
        for (int mf = 0; mf < 4; ++mf)
            for (int rg = 0; rg < 4; ++rg) {
                int b = m0 + wm * 64 + mf * 16 + hi * 4 + rg;
                float ig = acc[mf][0][rg];
                float gg = acc[mf][2][rg];
                float og = acc[mf][3][rg];
                float cn = sigf(ig) * tanh_f(gg);
                size_t off = (size_t)b * 1024 + h;
                c[off] = cn;
                hb1[off] = f2bf(sigf(og) * tanh_f(cn));
            }
    } else {
        for (int mf = 0; mf < 4; ++mf)
            for (int nf = 0; nf < 4; ++nf)
                for (int rg = 0; rg < 4; ++rg) {
                    int row = m0 + wm * 64 + mf * 16 + hi * 4 + rg;
                    int col = n0 + wn * 64 + nf * 16 + hl;
                    xg[(size_t)row * 4096 + col] = f2bf(acc[mf][nf][rg]);
                }
    }
}

// ---------------- LSTM recurrent step (512 x 128, BN'=64, dbuf counted-vmcnt) ----------------

__global__ __launch_bounds__(128) void lstm_step(const short* __restrict__ hin,  // [256][1024]
                                                 const short* __restrict__ Wstk, // [4096][1344]
                                                 const short* __restrict__ xg_t, // [256][4096]
                                                 float* __restrict__ c,          // [256][1024]
                                                 short* __restrict__ hout) {
    __shared__ __attribute__((aligned(16))) short As[2][32 * 128];
    __shared__ __attribute__((aligned(16))) short Bs[2][64 * 128];
    const int tid = threadIdx.x, l = tid & 63, w = tid >> 6;
    const int hi = l >> 4, hl = l & 15;
    const int bid = blockIdx.x;             // 512
    const int xcd = bid & 7, ii = bid >> 3;
    const int ny = xcd * 8 + (ii & 7);      // n' panel [0,64)
    const int mx = ii >> 3;                 // m panel [0,8)
    const int m0 = mx * 32, n0g = ny * 64;

    f32x4 acc[4];
    for (int i = 0; i < 4; i++) acc[i] = f32x4{0.f, 0.f, 0.f, 0.f};

    const short* asrc[4];
    const short* bsrc[8];
    for (int i = 0; i < 4; i++) {
        int s = i * 128 + tid;
        int r = s >> 4, cs = s & 15;
        asrc[i] = hin + (size_t)(m0 + r) * 1024 + ((cs ^ (r & 15)) * 8);
    }
    for (int i = 0; i < 8; i++) {
        int s = i * 128 + tid;
        int r = s >> 4, cs = s & 15;
        bsrc[i] = Wstk + (size_t)(n0g + r) * 1344 + 320 + ((cs ^ (r & 15)) * 8);
    }
    for (int i = 0; i < 4; i++) gload16(asrc[i], &As[0][(i * 128 + tid) * 8]);
    for (int i = 0; i < 8; i++) gload16(bsrc[i], &Bs[0][(i * 128 + tid) * 8]);

    for (int kt = 0; kt < 8; ++kt) {
        const int cur = kt & 1;
        if (kt < 7) {
            const int k0 = (kt + 1) * 128;
            for (int i = 0; i < 4; i++)
                gload16(asrc[i] + k0, &As[cur ^ 1][(i * 128 + tid) * 8]);
            for (int i = 0; i < 8; i++)
                gload16(bsrc[i] + k0, &Bs[cur ^ 1][(i * 128 + tid) * 8]);
            asm volatile("s_waitcnt vmcnt(12)" ::: "memory");
        } else {
            asm volatile("s_waitcnt vmcnt(0)" ::: "memory");
        }
        __builtin_amdgcn_sched_barrier(0);
        __builtin_amdgcn_s_barrier();
        __builtin_amdgcn_sched_barrier(0);
#pragma unroll
        for (int ks = 0; ks < 4; ++ks) {
            const int mrow = w * 16 + hl;
            const int ca = (ks * 4 + hi) ^ hl;
            short8 a = *(const short8*)&As[cur][mrow * 128 + ca * 8];
#pragma unroll
            for (int nf = 0; nf < 4; ++nf) {
                const int nrow = nf * 16 + hl;
                short8 b = *(const short8*)&Bs[cur][nrow * 128 + ca * 8];
                acc[nf] = mfma16(a, b, acc[nf]);
            }
        }
        __builtin_amdgcn_sched_barrier(0);
        asm volatile("s_waitcnt lgkmcnt(0)" ::: "memory");
        __builtin_amdgcn_s_barrier();
        __builtin_amdgcn_sched_barrier(0);
    }

    const short* xr0 = xg_t + (size_t)(m0 + w * 16 + hi * 4) * 4096 + n0g + hl;
    for (int rg = 0; rg < 4; ++rg) {
        const short* xr = xr0 + (size_t)rg * 4096;
        float ig = acc[0][rg] + bf2f(xr[0]);
        float fg = acc[1][rg] + bf2f(xr[16]);
        float gg = acc[2][rg] + bf2f(xr[32]);
        float og = acc[3][rg] + bf2f(xr[48]);
        size_t off = (size_t)(m0 + w * 16 + hi * 4 + rg) * 1024 + ny * 16 + hl;
        float cn = sigf(fg) * c[off] + sigf(ig) * tanh_f(gg);
        c[off] = cn;
        hout[off] = f2bf(sigf(og) * tanh_f(cn));
    }
}

// ---------------- gated MLP: BM=256 x BN=128, 8 waves, single-buffer ----------------

__global__ __launch_bounds__(512) void mlp_gemm(const short* __restrict__ Ac,   // [25600][2048]
                                                const short* __restrict__ hb,   // [256][1024]
                                                const short* __restrict__ Wcat, // [1024][3072]
                                                const int* __restrict__ mliveptr,
                                                const int* __restrict__ bmap,
                                                const float* __restrict__ Wb,
                                                const float* __restrict__ Wpb,
                                                const float* __restrict__ fw,
                                                float* __restrict__ logits) {
    __shared__ __attribute__((aligned(16))) short As[256 * 64];   // 32 KB
    __shared__ __attribute__((aligned(16))) short Bs[128 * 64];   // 16 KB
    const int Mlive = *mliveptr;
    const int tid = threadIdx.x, l = tid & 63, w = tid >> 6;      // w 0..7
    const int bid = blockIdx.x;              // 800
    const int xcd = bid & 7, ii = bid >> 3;  // ii 0..99
    const int x = ii & 7, q = ii >> 3;       // q 0..12
    const int y = q * 8 + xcd;
    const int n0 = x * 128, m0 = y * 256;
    if (m0 >= Mlive) return;
    const int wm = w >> 1, wn = w & 1;

    const short* asrc[4];
    const short* hsrc[4];
    int adst[4];
    const short* bsrc[2];
    int bdst[2];
    for (int i = 0; i < 4; i++) {
        int r = i * 64 + w * 8 + (l >> 3);           // 0..255
        int cs = (l & 7) ^ (r & 7);
        asrc[i] = Ac + (size_t)(m0 + r) * 2048 + cs * 8;
        hsrc[i] = hb + (size_t)bmap[m0 + r] * 1024 + cs * 8;
        adst[i] = (i * 64 + w * 8) * 64;
    }
    for (int i = 0; i < 2; i++) {
        int r = i * 64 + w * 8 + (l >> 3);           // 0..127
        int cs = (l & 7) ^ (r & 7);
        bsrc[i] = Wcat + (size_t)(n0 + r) * 3072 + cs * 8;
        bdst[i] = (i * 64 + w * 8) * 64;
    }

    f32x4 acc[4][4];
    for (int i = 0; i < 4; i++)
        for (int j = 0; j < 4; j++) acc[i][j] = f32x4{0.f, 0.f, 0.f, 0.f};

    for (int kt = 0; kt < 48; ++kt) {
        const int k0 = kt * 64;
        __syncthreads();
        if (kt < 32) {
            for (int i = 0; i < 4; i++)
                gload16(asrc[i] + k0, &As[adst[i]]);
        } else {
            const int kq = k0 - 2048;
            for (int i = 0; i < 4; i++)
                gload16(hsrc[i] + kq, &As[adst[i]]);
        }
        for (int i = 0; i < 2; i++)
            gload16(bsrc[i] + k0, &Bs[bdst[i]]);
        __syncthreads();
        for (int ks = 0; ks < 2; ++ks) {
            short8 a[4], b[4];
            for (int mf = 0; mf < 4; ++mf) {
                int m = wm * 64 + mf * 16 + (l & 15);   // 0..255
                int ca = (ks * 4 + (l >> 4)) ^ (m & 7);
                a[mf] = *(const short8*)&As[m * 64 + ca * 8];
            }
            for (int nf = 0; nf < 4; ++nf) {
                int n = wn * 64 + nf * 16 + (l & 15);   // 0..127
                int cb = (ks * 4 + (l >> 4)) ^ (n & 7);
                b[nf] = *(const short8*)&Bs[n * 64 + cb * 8];
            }
            for (int mf = 0; mf < 4; ++mf)
                for (int nf = 0; nf < 4; ++nf)
                    acc[mf][nf] = mfma16(a[mf], b[nf], acc[mf][nf]);
        }
    }

    const int hl = l & 15, hi = l >> 4;
    for (int mf = 0; mf < 4; ++mf) {
        float part[4] = {0.f, 0.f, 0.f, 0.f};
        for (int p = 0; p < 2; ++p) {
            int ntg = (n0 + wn * 64) / 16 + 2 * p;
            int hg = ntg >> 1;
            int h = hg * 16 + hl;
            float fwv = fw[h], wbv = Wb[h], wpbv = Wpb[h];
            for (int rg = 0; rg < 4; ++rg) {
                float y2 = tanh_f(acc[mf][2 * p][rg] + wbv);
                float g2 = sigf(acc[mf][2 * p + 1][rg] + wpbv);
                part[rg] += y2 * g2 * fwv;
            }
        }
        for (int rg = 0; rg < 4; ++rg) {
            float v = part[rg];
            v += __shfl_xor(v, 1, 64);
            v += __shfl_xor(v, 2, 64);
            v += __shfl_xor(v, 4, 64);
            v += __shfl_xor(v, 8, 64);
            if (hl == 0) {
                int row = m0 + wm * 64 + mf * 16 + hi * 4 + rg;
                atomicAdd(&logits[row], v);
            }
        }
    }
}

__global__ __launch_bounds__(128) void reduce_out(const float* __restrict__ logits,
                                                  const int* __restrict__ index,
                                                  const int* __restrict__ cum,
                                                  float* __restrict__ out) {
    int b = blockIdx.x, t = threadIdx.x;
    int idx = index[b];
    int base = cum[b];
    float v = 0.f;
    if (t < 100 && t < idx) v = sigf(logits[base + t]);
    for (int m = 32; m; m >>= 1) v += __shfl_down(v, m, 64);
    __shared__ float s[2];
    if ((t & 63) == 0) s[t >> 6] = v;
    __syncthreads();
    if (t == 0) out[b] = s[0] + s[1];
}

// ---------------- host ----------------

extern "C" void kernel_launch(void* const* d_in, const int* in_sizes, int n_in,
                              void* d_out, int out_size, void* d_ws, size_t ws_size,
                              hipStream_t stream) {
    (void)in_sizes; (void)n_in; (void)out_size; (void)ws_size;
    const float* box = (const float*)d_in[2];
    const float* qf  = (const float*)d_in[3];
    const int* index = (const int*)d_in[5];
    const float* Wih = (const float*)d_in[6];
    const float* Whh = (const float*)d_in[7];
    const float* bih = (const float*)d_in[8];
    const float* bhh = (const float*)d_in[9];
    const float* Ww  = (const float*)d_in[10];
    const float* Wb  = (const float*)d_in[11];
    const float* Wpw = (const float*)d_in[12];
    const float* Wpb = (const float*)d_in[13];
    const float* fw  = (const float*)d_in[14];

    char* p = (char*)d_ws;
    short* Wstk = (short*)p;  p += (size_t)4096 * 1344 * 2;
    short* Wcat = (short*)p;  p += (size_t)1024 * 3072 * 2;
    short* xb   = (short*)p;  p += (size_t)3584 * 320 * 2;
    short* hb0  = (short*)p;  p += (size_t)256 * 1024 * 2;
    short* hb1  = (short*)p;  p += (size_t)256 * 1024 * 2;
    short* xg   = (short*)p;  p += (size_t)3584 * 4096 * 2;
    float* c    = (float*)p;  p += (size_t)256 * 1024 * 4;
    int*   cum  = (int*)p;    p += 260 * 4;
    int*   bmap = (int*)p;    p += (size_t)(25600 + 256) * 4;
    float* lgt  = (float*)p;  p += (size_t)25600 * 4;
    p = (char*)(((uintptr_t)p + 255) & ~(uintptr_t)255);
    short* Ac   = (short*)p;  p += (size_t)25600 * 2048 * 2;   // ~105 MB

    prep_all<<<1 + PREP_TOT / 256, 256, 0, stream>>>(
        index, Wih, Whh, bih, bhh, qf, cum, bmap, Wstk, xb, lgt);

    // fused: xg GEMM (+t=0 cell -> c, hb1), box compaction -> Ac, Wcat prep
    compact_xg<<<896 + 25600 + WC_SLOTS / 256, 256, 0, stream>>>(
        xb, Wstk, xg, c, hb1, box, index, cum, Ac, Ww, Wpw, Wcat);

    short* hbuf[2] = {hb0, hb1};
    for (int t = 1; t < 14; ++t) {
        lstm_step<<<512, 128, 0, stream>>>(
            hbuf[t & 1], Wstk, xg + (size_t)t * 256 * 4096, c, hbuf[(t & 1) ^ 1]);
    }
    // t=13 reads hb1, writes hb0 -> final hidden state h_14 in hb0

    mlp_gemm<<<800, 512, 0, stream>>>(Ac, hb0, Wcat, cum + 256, bmap,
                                      Wb, Wpb, fw, lgt);
    reduce_out<<<256, 128, 0, stream>>>(lgt, index, cum, (float*)d_out);
}